// Round 1
// baseline (561.722 us; speedup 1.0000x reference)
//
#include <hip/hip_runtime.h>

// Problem constants
#define NAG 8
#define BB 32768
#define SDIM 128
#define ADIM 16
#define HID 128
#define IDIM 144

typedef unsigned short u16;
typedef unsigned int u32;
typedef __attribute__((ext_vector_type(8))) short short8;
typedef __attribute__((ext_vector_type(4))) float floatx4;

__device__ __forceinline__ u16 f2bf(float f) {
  u32 u = __float_as_uint(f);
  u32 r = (u + 0x7FFFu + ((u >> 16) & 1u)) >> 16;  // RNE
  return (u16)r;
}
__device__ __forceinline__ float bflo(u32 u) { return __uint_as_float(u << 16); }
__device__ __forceinline__ float bfhi(u32 u) { return __uint_as_float(u & 0xFFFF0000u); }

// ---------------------------------------------------------------------------
// ws layout (u16 element offsets):
//  WeP   @ 0        len 163840  (8 agents x [5kc][8ct][64][8])
//  WsP   @ 163840   len 131072  (8 x 4kc)
//  WkP   @ 294912   len 16384
//  WvP   @ 311296   len 16384
//  WqP   @ 327680   len 16384
//  Wc1P  @ 344064   len 262144  (8 x 8kc)
//  Kbuf  @ 606208   len 33554432   [n][B][128] bf16
//  Vbuf  @ 34160640 len 33554432
//  Qbuf  @ 67715072 len 33554432
//  CI    @ 101269504 len 67108864  [n][B][256] bf16 (s_enc | other)
// total 336,756,736 bytes
// ---------------------------------------------------------------------------

// Weight prep: fp32 -> bf16, MFMA B-frag-major layout:
// dst[((kc*8+ct)*64+lane)*8+j] = W[kc*32+(lane>>4)*8+j][ct*16+(lane&15)]
__global__ void prep_kernel(const float* __restrict__ We, const float* __restrict__ Ws,
                            const float* __restrict__ Wk, const float* __restrict__ Wq,
                            const float* __restrict__ Wv, const float* __restrict__ Wc1,
                            u16* __restrict__ ws) {
  int idx = blockIdx.x * 256 + threadIdx.x;
  const float* src;
  u16* dst;
  int e, Kreal, mode = 0;
  if (idx < 163840) {
    int a = idx / 20480; e = idx % 20480;
    src = We + a * (IDIM * HID); dst = ws + a * 20480; Kreal = IDIM;
  } else if (idx < 294912) {
    int r = idx - 163840; int a = r >> 14; e = r & 16383;
    src = Ws + a * 16384; dst = ws + 163840 + a * 16384; Kreal = 128;
  } else if (idx < 311296) {
    e = idx - 294912; src = Wk; dst = ws + 294912; Kreal = 128; mode = 1;
  } else if (idx < 327680) {
    e = idx - 311296; src = Wv; dst = ws + 311296; Kreal = 128; mode = 1;
  } else if (idx < 344064) {
    e = idx - 327680; src = Wq; dst = ws + 327680; Kreal = 128; mode = 1;
  } else if (idx < 606208) {
    int r = idx - 344064; int a = r >> 15; e = r & 32767;
    src = Wc1 + a * 32768; dst = ws + 344064 + a * 32768; Kreal = 256;
  } else {
    return;
  }
  int j = e & 7, lane = (e >> 3) & 63, ct = (e >> 9) & 7, kc = e >> 12;
  int k = kc * 32 + ((lane >> 4) << 3) + j;
  int c = ct * 16 + (lane & 15);
  float val = 0.f;
  if (k < Kreal)
    val = mode ? src[((c >> 5) * 128 + k) * 32 + (c & 31)]   // head-combined [H][HID][AD]
               : src[k * 128 + c];
  dst[e] = f2bf(val);
}

// MFMA helper: wave computes 16 rows x 128 cols, A from LDS row-major (bf16),
// W from LDS in frag-major layout. Verified layouts:
//   A-frag: lane l -> A[l&15][kc*32 + (l>>4)*8 + j]
//   C/D:    col = lane&15, row = (lane>>4)*4 + reg
template <int NKC>
__device__ __forceinline__ void gemm8(const u16* A, const int astride, const u16* W,
                                      const int wave, const int lane, floatx4* acc) {
  const int arow = wave * 16 + (lane & 15);
  const int koff = (lane >> 4) << 3;
#pragma unroll
  for (int kc = 0; kc < NKC; ++kc) {
    short8 a = *(const short8*)&A[arow * astride + kc * 32 + koff];
#pragma unroll
    for (int ct = 0; ct < 8; ++ct) {
      short8 b = *(const short8*)&W[kc * 4096 + ct * 512 + lane * 8];
      acc[ct] = __builtin_amdgcn_mfma_f32_16x16x32_bf16(a, b, acc[ct], 0, 0, 0);
    }
  }
}

// k1: per (agent, 128-b tile): sa_enc, s_enc, K, V, Q. 512 threads = 8 waves.
__global__ __launch_bounds__(512) void k1_kernel(
    const float* __restrict__ states, const float* __restrict__ actions,
    const float* __restrict__ be, const float* __restrict__ bs, const float* __restrict__ bv,
    const u16* __restrict__ wsbase,
    u16* __restrict__ Kbuf, u16* __restrict__ Vbuf, u16* __restrict__ Qbuf,
    u16* __restrict__ CI) {
  __shared__ __align__(16) u16 Alds[128 * 168];  // inp tile, K padded to 160 (+8 pad)
  __shared__ __align__(16) u16 Wb[20480];        // weight frags (max 5 kc)
  __shared__ __align__(16) u16 E1[128 * 136];    // sa_enc bf16
  __shared__ __align__(16) u16 E2[128 * 136];    // s_enc bf16

  const int tid = threadIdx.x, lane = tid & 63, wave = tid >> 6;
  const int n = blockIdx.y;
  const size_t b0 = (size_t)blockIdx.x * 128;
  const int colb = lane & 15;
  const int rowl = wave * 16 + ((lane >> 4) << 2);

  const u16* WeP = wsbase;
  const u16* WsP = wsbase + 163840;
  const u16* WkP = wsbase + 294912;
  const u16* WvP = wsbase + 311296;
  const u16* WqP = wsbase + 327680;

  // ---- stage inp tile (states | actions | zero-pad) as bf16
  {
    const float4* sp = (const float4*)(states + ((size_t)n * BB + b0) * SDIM);
#pragma unroll
    for (int it = 0; it < 8; ++it) {
      int c = tid + it * 512;
      float4 v = sp[c];
      int row = c >> 5, col = (c & 31) << 2;
      *(uint2*)&Alds[row * 168 + col] =
          make_uint2((u32)f2bf(v.x) | ((u32)f2bf(v.y) << 16),
                     (u32)f2bf(v.z) | ((u32)f2bf(v.w) << 16));
    }
    const float4* apt = (const float4*)(actions + ((size_t)n * BB + b0) * ADIM);
    {
      float4 v = apt[tid];
      int row = tid >> 2, col = 128 + ((tid & 3) << 2);
      *(uint2*)&Alds[row * 168 + col] =
          make_uint2((u32)f2bf(v.x) | ((u32)f2bf(v.y) << 16),
                     (u32)f2bf(v.z) | ((u32)f2bf(v.w) << 16));
    }
    {
      int row = tid >> 2, col = 144 + ((tid & 3) << 2);
      *(uint2*)&Alds[row * 168 + col] = make_uint2(0u, 0u);
    }
    const uint4* s4 = (const uint4*)(WeP + (size_t)n * 20480);
    uint4* d4 = (uint4*)Wb;
#pragma unroll
    for (int it = 0; it < 5; ++it) d4[tid + it * 512] = s4[tid + it * 512];
  }
  __syncthreads();

  floatx4 acc[8];

  // ---- E1 = relu(inp @ We + be)
#pragma unroll
  for (int ct = 0; ct < 8; ++ct) acc[ct] = (floatx4){0.f, 0.f, 0.f, 0.f};
  gemm8<5>(Alds, 168, Wb, wave, lane, acc);
#pragma unroll
  for (int ct = 0; ct < 8; ++ct) {
    int col = ct * 16 + colb;
    float bb = be[n * HID + col];
#pragma unroll
    for (int r = 0; r < 4; ++r)
      E1[(rowl + r) * 136 + col] = f2bf(fmaxf(acc[ct][r] + bb, 0.f));
  }
  __syncthreads();
  {
    const uint4* s4 = (const uint4*)(WsP + (size_t)n * 16384);
    uint4* d4 = (uint4*)Wb;
#pragma unroll
    for (int it = 0; it < 4; ++it) d4[tid + it * 512] = s4[tid + it * 512];
  }
  __syncthreads();

  // ---- E2 = relu(states @ Ws + bs); also write s_enc -> CI[:,0:128]
#pragma unroll
  for (int ct = 0; ct < 8; ++ct) acc[ct] = (floatx4){0.f, 0.f, 0.f, 0.f};
  gemm8<4>(Alds, 168, Wb, wave, lane, acc);
#pragma unroll
  for (int ct = 0; ct < 8; ++ct) {
    int col = ct * 16 + colb;
    float bb = bs[n * HID + col];
#pragma unroll
    for (int r = 0; r < 4; ++r) {
      u16 u = f2bf(fmaxf(acc[ct][r] + bb, 0.f));
      E2[(rowl + r) * 136 + col] = u;
      CI[((size_t)n * BB + b0 + rowl + r) * 256 + col] = u;
    }
  }
  __syncthreads();
  {
    const uint4* s4 = (const uint4*)WkP;
    uint4* d4 = (uint4*)Wb;
#pragma unroll
    for (int it = 0; it < 4; ++it) d4[tid + it * 512] = s4[tid + it * 512];
  }
  __syncthreads();

  // ---- K = E1 @ Wk_all
#pragma unroll
  for (int ct = 0; ct < 8; ++ct) acc[ct] = (floatx4){0.f, 0.f, 0.f, 0.f};
  gemm8<4>(E1, 136, Wb, wave, lane, acc);
#pragma unroll
  for (int ct = 0; ct < 8; ++ct) {
    int col = ct * 16 + colb;
#pragma unroll
    for (int r = 0; r < 4; ++r)
      Kbuf[((size_t)n * BB + b0 + rowl + r) * HID + col] = f2bf(acc[ct][r]);
  }
  __syncthreads();
  {
    const uint4* s4 = (const uint4*)WvP;
    uint4* d4 = (uint4*)Wb;
#pragma unroll
    for (int it = 0; it < 4; ++it) d4[tid + it * 512] = s4[tid + it * 512];
  }
  __syncthreads();

  // ---- V = relu(E1 @ Wv_all + bv)
#pragma unroll
  for (int ct = 0; ct < 8; ++ct) acc[ct] = (floatx4){0.f, 0.f, 0.f, 0.f};
  gemm8<4>(E1, 136, Wb, wave, lane, acc);
#pragma unroll
  for (int ct = 0; ct < 8; ++ct) {
    int col = ct * 16 + colb;
    float bb = bv[col];  // bv flat [H][AD] == col index
#pragma unroll
    for (int r = 0; r < 4; ++r)
      Vbuf[((size_t)n * BB + b0 + rowl + r) * HID + col] = f2bf(fmaxf(acc[ct][r] + bb, 0.f));
  }
  __syncthreads();
  {
    const uint4* s4 = (const uint4*)WqP;
    uint4* d4 = (uint4*)Wb;
#pragma unroll
    for (int it = 0; it < 4; ++it) d4[tid + it * 512] = s4[tid + it * 512];
  }
  __syncthreads();

  // ---- Q = E2 @ Wq_all
#pragma unroll
  for (int ct = 0; ct < 8; ++ct) acc[ct] = (floatx4){0.f, 0.f, 0.f, 0.f};
  gemm8<4>(E2, 136, Wb, wave, lane, acc);
#pragma unroll
  for (int ct = 0; ct < 8; ++ct) {
    int col = ct * 16 + colb;
#pragma unroll
    for (int r = 0; r < 4; ++r)
      Qbuf[((size_t)n * BB + b0 + rowl + r) * HID + col] = f2bf(acc[ct][r]);
  }
}

// k2: cross-agent attention. thread = (b, head); loops agents i.
__global__ __launch_bounds__(256) void k2_kernel(const u16* __restrict__ Kb,
                                                 const u16* __restrict__ Vb,
                                                 const u16* __restrict__ Qb,
                                                 u16* __restrict__ CI) {
  const int tid = threadIdx.x;
  const size_t b = (size_t)blockIdx.x * 64 + (tid & 63);
  const int h = tid >> 6;
  const float scale = 0.17677669529663687f;  // 1/sqrt(32)
#pragma unroll 1
  for (int i = 0; i < 8; ++i) {
    const u32* qp = (const u32*)(Qb + ((size_t)i * BB + b) * HID + h * 32);
    float q[32];
#pragma unroll
    for (int t = 0; t < 16; ++t) {
      u32 u = qp[t];
      q[2 * t] = bflo(u);
      q[2 * t + 1] = bfhi(u);
    }
    float lg[8];
#pragma unroll
    for (int j = 0; j < 8; ++j) {
      if (j != i) {  // wave-uniform branch (i uniform)
        const u32* kp = (const u32*)(Kb + ((size_t)j * BB + b) * HID + h * 32);
        float acc = 0.f;
#pragma unroll
        for (int t = 0; t < 16; ++t) {
          u32 u = kp[t];
          acc = fmaf(bflo(u), q[2 * t], acc);
          acc = fmaf(bfhi(u), q[2 * t + 1], acc);
        }
        lg[j] = acc * scale;
      } else {
        lg[j] = -1e9f;  // exact reference masking
      }
    }
    float m = lg[0];
#pragma unroll
    for (int j = 1; j < 8; ++j) m = fmaxf(m, lg[j]);
    float p[8], s = 0.f;
#pragma unroll
    for (int j = 0; j < 8; ++j) {
      p[j] = __expf(lg[j] - m);
      s += p[j];
    }
    const float inv = 1.f / s;
    float o[32];
#pragma unroll
    for (int d = 0; d < 32; ++d) o[d] = 0.f;
#pragma unroll
    for (int j = 0; j < 8; ++j) {
      if (j == i) continue;
      const float pj = p[j] * inv;
      const u32* vp = (const u32*)(Vb + ((size_t)j * BB + b) * HID + h * 32);
#pragma unroll
      for (int t = 0; t < 16; ++t) {
        u32 u = vp[t];
        o[2 * t] = fmaf(pj, bflo(u), o[2 * t]);
        o[2 * t + 1] = fmaf(pj, bfhi(u), o[2 * t + 1]);
      }
    }
    u32 ow[16];
#pragma unroll
    for (int t = 0; t < 16; ++t)
      ow[t] = (u32)f2bf(o[2 * t]) | ((u32)f2bf(o[2 * t + 1]) << 16);
    uint4* op = (uint4*)(CI + ((size_t)i * BB + b) * 256 + 128 + h * 32);
    op[0] = make_uint4(ow[0], ow[1], ow[2], ow[3]);
    op[1] = make_uint4(ow[4], ow[5], ow[6], ow[7]);
    op[2] = make_uint4(ow[8], ow[9], ow[10], ow[11]);
    op[3] = make_uint4(ow[12], ow[13], ow[14], ow[15]);
  }
}

// k3: critic. h1 = relu(CI @ Wc1 + bc1); q = h1 . Wc2[:, argmax(actions)] + bc2
__global__ __launch_bounds__(512) void k3_kernel(
    const u16* __restrict__ CI, const u16* __restrict__ Wc1P, const float* __restrict__ bc1,
    const float* __restrict__ Wc2, const float* __restrict__ bc2,
    const float* __restrict__ actions, float* __restrict__ out) {
  __shared__ __align__(16) u16 Alds[128 * 264];  // A tile; later reused for H1 (stride 136)
  __shared__ __align__(16) u16 Wb[32768];
  __shared__ __align__(16) float Wc2s[2048];

  const int tid = threadIdx.x, lane = tid & 63, wave = tid >> 6;
  const int n = blockIdx.y;
  const size_t b0 = (size_t)blockIdx.x * 128;
  const int colb = lane & 15;
  const int rowl = wave * 16 + ((lane >> 4) << 2);

  {
    const uint4* src = (const uint4*)(CI + ((size_t)n * BB + b0) * 256);
    uint4* dstA = (uint4*)Alds;
#pragma unroll
    for (int it = 0; it < 8; ++it) {
      int c = tid + it * 512;
      int row = c >> 5, c16 = c & 31;
      dstA[row * 33 + c16] = src[c];  // LDS row stride = 264 u16 = 33 uint4
    }
    const uint4* wsrc = (const uint4*)(Wc1P + (size_t)n * 32768);
    uint4* wdst = (uint4*)Wb;
#pragma unroll
    for (int it = 0; it < 8; ++it) wdst[tid + it * 512] = wsrc[tid + it * 512];
    ((float4*)Wc2s)[tid] = ((const float4*)(Wc2 + n * 2048))[tid];
  }
  __syncthreads();

  floatx4 acc[8];
#pragma unroll
  for (int ct = 0; ct < 8; ++ct) acc[ct] = (floatx4){0.f, 0.f, 0.f, 0.f};
  gemm8<8>(Alds, 264, Wb, wave, lane, acc);
  __syncthreads();  // everyone done reading A before H1 overwrites it

#pragma unroll
  for (int ct = 0; ct < 8; ++ct) {
    int col = ct * 16 + colb;
    float bb = bc1[n * HID + col];
#pragma unroll
    for (int r = 0; r < 4; ++r) {
      float v = fmaxf(acc[ct][r] + bb, 0.f);
      Alds[(rowl + r) * 136 + col] = f2bf(v);  // H1
    }
  }
  __syncthreads();

  {
    const int bloc = tid >> 2, part = tid & 3;
    const size_t b = b0 + bloc;
    const float* ap = actions + ((size_t)n * BB + b) * ADIM;
    int am = 0;
    float mv = ap[0];
#pragma unroll
    for (int t = 1; t < 16; ++t) {
      float v = ap[t];
      if (v > mv) { mv = v; am = t; }  // strict > keeps first max (argmax semantics)
    }
    float a2 = 0.f;
    const int cb = part * 32;
#pragma unroll
    for (int c2 = 0; c2 < 32; ++c2) {
      float hv = __uint_as_float((u32)Alds[bloc * 136 + cb + c2] << 16);
      a2 = fmaf(hv, Wc2s[(cb + c2) * 16 + am], a2);
    }
    a2 += __shfl_xor(a2, 1);
    a2 += __shfl_xor(a2, 2);
    if (part == 0) out[(size_t)n * BB + b] = a2 + bc2[n * ADIM + am];
  }
}

extern "C" void kernel_launch(void* const* d_in, const int* in_sizes, int n_in,
                              void* d_out, int out_size, void* d_ws, size_t ws_size,
                              hipStream_t stream) {
  const float* states  = (const float*)d_in[0];
  const float* actions = (const float*)d_in[1];
  const float* We  = (const float*)d_in[2];
  const float* be  = (const float*)d_in[3];
  const float* Ws  = (const float*)d_in[4];
  const float* bs  = (const float*)d_in[5];
  const float* Wk  = (const float*)d_in[6];
  const float* Wq  = (const float*)d_in[7];
  const float* Wv  = (const float*)d_in[8];
  const float* bv  = (const float*)d_in[9];
  const float* Wc1 = (const float*)d_in[10];
  const float* bc1 = (const float*)d_in[11];
  const float* Wc2 = (const float*)d_in[12];
  const float* bc2 = (const float*)d_in[13];
  float* out = (float*)d_out;
  u16* ws = (u16*)d_ws;

  u16* Kbuf = ws + 606208;
  u16* Vbuf = ws + 34160640;
  u16* Qbuf = ws + 67715072;
  u16* CI   = ws + 101269504;

  prep_kernel<<<2368, 256, 0, stream>>>(We, Ws, Wk, Wq, Wv, Wc1, ws);
  k1_kernel<<<dim3(256, 8), 512, 0, stream>>>(states, actions, be, bs, bv, ws,
                                              Kbuf, Vbuf, Qbuf, CI);
  k2_kernel<<<512, 256, 0, stream>>>(Kbuf, Vbuf, Qbuf, CI);
  k3_kernel<<<dim3(256, 8), 512, 0, stream>>>(CI, ws + 344064, bc1, Wc2, bc2, actions, out);
}

// Round 2
// 448.931 us; speedup vs baseline: 1.2512x; 1.2512x over previous
//
#include <hip/hip_runtime.h>

// Problem constants
#define NAG 8
#define BB 32768
#define SDIM 128
#define ADIM 16
#define HID 128
#define IDIM 144

typedef unsigned short u16;
typedef unsigned int u32;
typedef __attribute__((ext_vector_type(8))) short short8;
typedef __attribute__((ext_vector_type(4))) float floatx4;

__device__ __forceinline__ u16 f2bf(float f) {
  u32 u = __float_as_uint(f);
  u32 r = (u + 0x7FFFu + ((u >> 16) & 1u)) >> 16;  // RNE
  return (u16)r;
}
__device__ __forceinline__ float bflo(u32 u) { return __uint_as_float(u << 16); }
__device__ __forceinline__ float bfhi(u32 u) { return __uint_as_float(u & 0xFFFF0000u); }

// ---------------------------------------------------------------------------
// ws layout (u16 element offsets):
//  WeP   @ 0        len 163840  (8 agents x [5kc][8ct][64][8])
//  WsP   @ 163840   len 131072  (8 x 4kc)
//  WkP   @ 294912   len 16384
//  WvP   @ 311296   len 16384
//  WqP   @ 327680   len 16384
//  Wc1P  @ 344064   len 262144  (8 x 8kc)
//  Kbuf  @ 606208   len 33554432   [n][B][128] bf16
//  Vbuf  @ 34160640 len 33554432
//  Qbuf  @ 67715072 len 33554432
//  CI    @ 101269504 len 67108864  [n][B][256] bf16 (s_enc | other)
// ---------------------------------------------------------------------------

__global__ void prep_kernel(const float* __restrict__ We, const float* __restrict__ Ws,
                            const float* __restrict__ Wk, const float* __restrict__ Wq,
                            const float* __restrict__ Wv, const float* __restrict__ Wc1,
                            u16* __restrict__ ws) {
  int idx = blockIdx.x * 256 + threadIdx.x;
  const float* src;
  u16* dst;
  int e, Kreal, mode = 0;
  if (idx < 163840) {
    int a = idx / 20480; e = idx % 20480;
    src = We + a * (IDIM * HID); dst = ws + a * 20480; Kreal = IDIM;
  } else if (idx < 294912) {
    int r = idx - 163840; int a = r >> 14; e = r & 16383;
    src = Ws + a * 16384; dst = ws + 163840 + a * 16384; Kreal = 128;
  } else if (idx < 311296) {
    e = idx - 294912; src = Wk; dst = ws + 294912; Kreal = 128; mode = 1;
  } else if (idx < 327680) {
    e = idx - 311296; src = Wv; dst = ws + 311296; Kreal = 128; mode = 1;
  } else if (idx < 344064) {
    e = idx - 327680; src = Wq; dst = ws + 327680; Kreal = 128; mode = 1;
  } else if (idx < 606208) {
    int r = idx - 344064; int a = r >> 15; e = r & 32767;
    src = Wc1 + a * 32768; dst = ws + 344064 + a * 32768; Kreal = 256;
  } else {
    return;
  }
  int j = e & 7, lane = (e >> 3) & 63, ct = (e >> 9) & 7, kc = e >> 12;
  int k = kc * 32 + ((lane >> 4) << 3) + j;
  int c = ct * 16 + (lane & 15);
  float val = 0.f;
  if (k < Kreal)
    val = mode ? src[((c >> 5) * 128 + k) * 32 + (c & 31)]   // head-combined [H][HID][AD]
               : src[k * 128 + c];
  dst[e] = f2bf(val);
}

// MFMA helper: wave computes 16 rows x 128 cols, A from LDS row-major (bf16),
// W from LDS in frag-major layout. Verified layouts:
//   A-frag: lane l -> A[l&15][kc*32 + (l>>4)*8 + j]
//   C/D:    col = lane&15, row = (lane>>4)*4 + reg
template <int NKC>
__device__ __forceinline__ void gemm8(const u16* A, const int astride, const u16* W,
                                      const int wave, const int lane, floatx4* acc) {
  const int arow = wave * 16 + (lane & 15);
  const int koff = (lane >> 4) << 3;
#pragma unroll
  for (int kc = 0; kc < NKC; ++kc) {
    short8 a = *(const short8*)&A[arow * astride + kc * 32 + koff];
#pragma unroll
    for (int ct = 0; ct < 8; ++ct) {
      short8 b = *(const short8*)&W[kc * 4096 + ct * 512 + lane * 8];
      acc[ct] = __builtin_amdgcn_mfma_f32_16x16x32_bf16(a, b, acc[ct], 0, 0, 0);
    }
  }
}

// k1: per (agent, 128-b tile): sa_enc, s_enc, K, V, Q. 512 threads = 8 waves.
__global__ __launch_bounds__(512) void k1_kernel(
    const float* __restrict__ states, const float* __restrict__ actions,
    const float* __restrict__ be, const float* __restrict__ bs, const float* __restrict__ bv,
    const u16* __restrict__ wsbase,
    u16* __restrict__ Kbuf, u16* __restrict__ Vbuf, u16* __restrict__ Qbuf,
    u16* __restrict__ CI) {
  __shared__ __align__(16) u16 Alds[128 * 168];  // inp tile, K padded to 160 (+8 pad)
  __shared__ __align__(16) u16 Wb[20480];        // weight frags (max 5 kc)
  __shared__ __align__(16) u16 E1[128 * 136];    // sa_enc bf16
  __shared__ __align__(16) u16 E2[128 * 136];    // s_enc bf16

  const int tid = threadIdx.x, lane = tid & 63, wave = tid >> 6;
  const int n = blockIdx.y;
  const size_t b0 = (size_t)blockIdx.x * 128;
  const int colb = lane & 15;
  const int rowl = wave * 16 + ((lane >> 4) << 2);

  const u16* WeP = wsbase;
  const u16* WsP = wsbase + 163840;
  const u16* WkP = wsbase + 294912;
  const u16* WvP = wsbase + 311296;
  const u16* WqP = wsbase + 327680;

  // ---- stage inp tile (states | actions | zero-pad) as bf16
  {
    const float4* sp = (const float4*)(states + ((size_t)n * BB + b0) * SDIM);
#pragma unroll
    for (int it = 0; it < 8; ++it) {
      int c = tid + it * 512;
      float4 v = sp[c];
      int row = c >> 5, col = (c & 31) << 2;
      *(uint2*)&Alds[row * 168 + col] =
          make_uint2((u32)f2bf(v.x) | ((u32)f2bf(v.y) << 16),
                     (u32)f2bf(v.z) | ((u32)f2bf(v.w) << 16));
    }
    const float4* apt = (const float4*)(actions + ((size_t)n * BB + b0) * ADIM);
    {
      float4 v = apt[tid];
      int row = tid >> 2, col = 128 + ((tid & 3) << 2);
      *(uint2*)&Alds[row * 168 + col] =
          make_uint2((u32)f2bf(v.x) | ((u32)f2bf(v.y) << 16),
                     (u32)f2bf(v.z) | ((u32)f2bf(v.w) << 16));
    }
    {
      int row = tid >> 2, col = 144 + ((tid & 3) << 2);
      *(uint2*)&Alds[row * 168 + col] = make_uint2(0u, 0u);
    }
    const uint4* s4 = (const uint4*)(WeP + (size_t)n * 20480);
    uint4* d4 = (uint4*)Wb;
#pragma unroll
    for (int it = 0; it < 5; ++it) d4[tid + it * 512] = s4[tid + it * 512];
  }
  __syncthreads();

  floatx4 acc[8];

  // ---- E1 = relu(inp @ We + be)
#pragma unroll
  for (int ct = 0; ct < 8; ++ct) acc[ct] = (floatx4){0.f, 0.f, 0.f, 0.f};
  gemm8<5>(Alds, 168, Wb, wave, lane, acc);
#pragma unroll
  for (int ct = 0; ct < 8; ++ct) {
    int col = ct * 16 + colb;
    float bb = be[n * HID + col];
#pragma unroll
    for (int r = 0; r < 4; ++r)
      E1[(rowl + r) * 136 + col] = f2bf(fmaxf(acc[ct][r] + bb, 0.f));
  }
  __syncthreads();
  {
    const uint4* s4 = (const uint4*)(WsP + (size_t)n * 16384);
    uint4* d4 = (uint4*)Wb;
#pragma unroll
    for (int it = 0; it < 4; ++it) d4[tid + it * 512] = s4[tid + it * 512];
  }
  __syncthreads();

  // ---- E2 = relu(states @ Ws + bs); also write s_enc -> CI[:,0:128]
#pragma unroll
  for (int ct = 0; ct < 8; ++ct) acc[ct] = (floatx4){0.f, 0.f, 0.f, 0.f};
  gemm8<4>(Alds, 168, Wb, wave, lane, acc);
#pragma unroll
  for (int ct = 0; ct < 8; ++ct) {
    int col = ct * 16 + colb;
    float bb = bs[n * HID + col];
#pragma unroll
    for (int r = 0; r < 4; ++r) {
      u16 u = f2bf(fmaxf(acc[ct][r] + bb, 0.f));
      E2[(rowl + r) * 136 + col] = u;
      CI[((size_t)n * BB + b0 + rowl + r) * 256 + col] = u;
    }
  }
  __syncthreads();
  {
    const uint4* s4 = (const uint4*)WkP;
    uint4* d4 = (uint4*)Wb;
#pragma unroll
    for (int it = 0; it < 4; ++it) d4[tid + it * 512] = s4[tid + it * 512];
  }
  __syncthreads();

  // ---- K = E1 @ Wk_all
#pragma unroll
  for (int ct = 0; ct < 8; ++ct) acc[ct] = (floatx4){0.f, 0.f, 0.f, 0.f};
  gemm8<4>(E1, 136, Wb, wave, lane, acc);
#pragma unroll
  for (int ct = 0; ct < 8; ++ct) {
    int col = ct * 16 + colb;
#pragma unroll
    for (int r = 0; r < 4; ++r)
      Kbuf[((size_t)n * BB + b0 + rowl + r) * HID + col] = f2bf(acc[ct][r]);
  }
  __syncthreads();
  {
    const uint4* s4 = (const uint4*)WvP;
    uint4* d4 = (uint4*)Wb;
#pragma unroll
    for (int it = 0; it < 4; ++it) d4[tid + it * 512] = s4[tid + it * 512];
  }
  __syncthreads();

  // ---- V = relu(E1 @ Wv_all + bv)
#pragma unroll
  for (int ct = 0; ct < 8; ++ct) acc[ct] = (floatx4){0.f, 0.f, 0.f, 0.f};
  gemm8<4>(E1, 136, Wb, wave, lane, acc);
#pragma unroll
  for (int ct = 0; ct < 8; ++ct) {
    int col = ct * 16 + colb;
    float bb = bv[col];  // bv flat [H][AD] == col index
#pragma unroll
    for (int r = 0; r < 4; ++r)
      Vbuf[((size_t)n * BB + b0 + rowl + r) * HID + col] = f2bf(fmaxf(acc[ct][r] + bb, 0.f));
  }
  __syncthreads();
  {
    const uint4* s4 = (const uint4*)WqP;
    uint4* d4 = (uint4*)Wb;
#pragma unroll
    for (int it = 0; it < 4; ++it) d4[tid + it * 512] = s4[tid + it * 512];
  }
  __syncthreads();

  // ---- Q = E2 @ Wq_all
#pragma unroll
  for (int ct = 0; ct < 8; ++ct) acc[ct] = (floatx4){0.f, 0.f, 0.f, 0.f};
  gemm8<4>(E2, 136, Wb, wave, lane, acc);
#pragma unroll
  for (int ct = 0; ct < 8; ++ct) {
    int col = ct * 16 + colb;
#pragma unroll
    for (int r = 0; r < 4; ++r)
      Qbuf[((size_t)n * BB + b0 + rowl + r) * HID + col] = f2bf(acc[ct][r]);
  }
}

// k2 v2: cross-agent attention with LDS-staged K/V (each HBM byte read once).
// Block = 16-b tile. 512 threads: wave = agent i (0..7), lane = h*16 + b.
// LDS layout per buffer: [j:8][b:16] rows of 256B = 16 chunks of 16B;
// chunk t stored at slot (t+b)&15 (rotation swizzle -> even bank-group spread).
__global__ __launch_bounds__(512, 4) void k2_kernel(const u16* __restrict__ Kb,
                                                    const u16* __restrict__ Vb,
                                                    const u16* __restrict__ Qb,
                                                    u16* __restrict__ CI) {
  __shared__ __align__(16) u16 Ksh[8 * 16 * 128];
  __shared__ __align__(16) u16 Vsh[8 * 16 * 128];

  const int tid = threadIdx.x;
  const int i = tid >> 6;          // wave = agent i
  const int lane = tid & 63;
  const int h = lane >> 4;         // head
  const int b = lane & 15;         // b within tile
  const size_t b0 = (size_t)blockIdx.x * 16;
  const float scale = 0.17677669529663687f;  // 1/sqrt(32)

  // ---- stage K and V for this b-tile, all 8 agents
  {
    uint4* kd = (uint4*)Ksh;
    uint4* vd = (uint4*)Vsh;
#pragma unroll
    for (int it = 0; it < 4; ++it) {
      int l = tid + it * 512;
      int j = l >> 8, bs_ = (l >> 4) & 15, t = l & 15;
      size_t gidx = ((size_t)j * BB + b0 + bs_) * 16 + t;  // uint4 units (128 u16 = 16 uint4)
      int slot = (t + bs_) & 15;
      int didx = (j * 16 + bs_) * 16 + slot;
      kd[didx] = ((const uint4*)Kb)[gidx];
      vd[didx] = ((const uint4*)Vb)[gidx];
    }
  }
  __syncthreads();

  // ---- load my Q (exactly once per element globally)
  float q[32];
  {
    const u32* qp = (const u32*)(Qb + ((size_t)i * BB + b0 + b) * HID + h * 32);
#pragma unroll
    for (int t = 0; t < 16; ++t) {
      u32 u = qp[t];
      q[2 * t] = bflo(u);
      q[2 * t + 1] = bfhi(u);
    }
  }

  // ---- logits
  float lg[8];
#pragma unroll
  for (int j = 0; j < 8; ++j) {
    if (j != i) {  // wave-uniform branch (i is per-wave constant)
      float acc = 0.f;
#pragma unroll
      for (int c = 0; c < 4; ++c) {
        int slot = ((h * 4 + c) + b) & 15;
        uint4 kv = *(const uint4*)&Ksh[((j * 16 + b) * 16 + slot) * 8];
        const u32 kw[4] = {kv.x, kv.y, kv.z, kv.w};
#pragma unroll
        for (int t = 0; t < 4; ++t) {
          int d = c * 8 + t * 2;
          acc = fmaf(bflo(kw[t]), q[d], acc);
          acc = fmaf(bfhi(kw[t]), q[d + 1], acc);
        }
      }
      lg[j] = acc * scale;
    } else {
      lg[j] = -1e9f;  // exact reference masking
    }
  }

  // ---- softmax (matches reference: max includes the -1e9 entry)
  float m = lg[0];
#pragma unroll
  for (int j = 1; j < 8; ++j) m = fmaxf(m, lg[j]);
  float p[8], s = 0.f;
#pragma unroll
  for (int j = 0; j < 8; ++j) {
    p[j] = __expf(lg[j] - m);
    s += p[j];
  }
  const float inv = 1.f / s;

  // ---- o = attn @ V
  float o[32];
#pragma unroll
  for (int d = 0; d < 32; ++d) o[d] = 0.f;
#pragma unroll
  for (int j = 0; j < 8; ++j) {
    if (j == i) continue;
    const float pj = p[j] * inv;
#pragma unroll
    for (int c = 0; c < 4; ++c) {
      int slot = ((h * 4 + c) + b) & 15;
      uint4 vv = *(const uint4*)&Vsh[((j * 16 + b) * 16 + slot) * 8];
      const u32 vw[4] = {vv.x, vv.y, vv.z, vv.w};
#pragma unroll
      for (int t = 0; t < 4; ++t) {
        int d = c * 8 + t * 2;
        o[d] = fmaf(pj, bflo(vw[t]), o[d]);
        o[d + 1] = fmaf(pj, bfhi(vw[t]), o[d + 1]);
      }
    }
  }

  // ---- pack & write `other`
  u32 ow[16];
#pragma unroll
  for (int t = 0; t < 16; ++t)
    ow[t] = (u32)f2bf(o[2 * t]) | ((u32)f2bf(o[2 * t + 1]) << 16);
  uint4* op = (uint4*)(CI + ((size_t)i * BB + b0 + b) * 256 + 128 + h * 32);
  op[0] = make_uint4(ow[0], ow[1], ow[2], ow[3]);
  op[1] = make_uint4(ow[4], ow[5], ow[6], ow[7]);
  op[2] = make_uint4(ow[8], ow[9], ow[10], ow[11]);
  op[3] = make_uint4(ow[12], ow[13], ow[14], ow[15]);
}

// k3: critic. h1 = relu(CI @ Wc1 + bc1); q = h1 . Wc2[:, argmax(actions)] + bc2
__global__ __launch_bounds__(512) void k3_kernel(
    const u16* __restrict__ CI, const u16* __restrict__ Wc1P, const float* __restrict__ bc1,
    const float* __restrict__ Wc2, const float* __restrict__ bc2,
    const float* __restrict__ actions, float* __restrict__ out) {
  __shared__ __align__(16) u16 Alds[128 * 264];  // A tile; later reused for H1 (stride 136)
  __shared__ __align__(16) u16 Wb[32768];
  __shared__ __align__(16) float Wc2s[2048];

  const int tid = threadIdx.x, lane = tid & 63, wave = tid >> 6;
  const int n = blockIdx.y;
  const size_t b0 = (size_t)blockIdx.x * 128;
  const int colb = lane & 15;
  const int rowl = wave * 16 + ((lane >> 4) << 2);

  {
    const uint4* src = (const uint4*)(CI + ((size_t)n * BB + b0) * 256);
    uint4* dstA = (uint4*)Alds;
#pragma unroll
    for (int it = 0; it < 8; ++it) {
      int c = tid + it * 512;
      int row = c >> 5, c16 = c & 31;
      dstA[row * 33 + c16] = src[c];  // LDS row stride = 264 u16 = 33 uint4
    }
    const uint4* wsrc = (const uint4*)(Wc1P + (size_t)n * 32768);
    uint4* wdst = (uint4*)Wb;
#pragma unroll
    for (int it = 0; it < 8; ++it) wdst[tid + it * 512] = wsrc[tid + it * 512];
    ((float4*)Wc2s)[tid] = ((const float4*)(Wc2 + n * 2048))[tid];
  }
  __syncthreads();

  floatx4 acc[8];
#pragma unroll
  for (int ct = 0; ct < 8; ++ct) acc[ct] = (floatx4){0.f, 0.f, 0.f, 0.f};
  gemm8<8>(Alds, 264, Wb, wave, lane, acc);
  __syncthreads();  // everyone done reading A before H1 overwrites it

#pragma unroll
  for (int ct = 0; ct < 8; ++ct) {
    int col = ct * 16 + colb;
    float bb = bc1[n * HID + col];
#pragma unroll
    for (int r = 0; r < 4; ++r) {
      float v = fmaxf(acc[ct][r] + bb, 0.f);
      Alds[(rowl + r) * 136 + col] = f2bf(v);  // H1
    }
  }
  __syncthreads();

  {
    const int bloc = tid >> 2, part = tid & 3;
    const size_t b = b0 + bloc;
    const float* ap = actions + ((size_t)n * BB + b) * ADIM;
    int am = 0;
    float mv = ap[0];
#pragma unroll
    for (int t = 1; t < 16; ++t) {
      float v = ap[t];
      if (v > mv) { mv = v; am = t; }  // strict > keeps first max (argmax semantics)
    }
    float a2 = 0.f;
    const int cb = part * 32;
#pragma unroll
    for (int c2 = 0; c2 < 32; ++c2) {
      float hv = __uint_as_float((u32)Alds[bloc * 136 + cb + c2] << 16);
      a2 = fmaf(hv, Wc2s[(cb + c2) * 16 + am], a2);
    }
    a2 += __shfl_xor(a2, 1);
    a2 += __shfl_xor(a2, 2);
    if (part == 0) out[(size_t)n * BB + b] = a2 + bc2[n * ADIM + am];
  }
}

extern "C" void kernel_launch(void* const* d_in, const int* in_sizes, int n_in,
                              void* d_out, int out_size, void* d_ws, size_t ws_size,
                              hipStream_t stream) {
  const float* states  = (const float*)d_in[0];
  const float* actions = (const float*)d_in[1];
  const float* We  = (const float*)d_in[2];
  const float* be  = (const float*)d_in[3];
  const float* Ws  = (const float*)d_in[4];
  const float* bs  = (const float*)d_in[5];
  const float* Wk  = (const float*)d_in[6];
  const float* Wq  = (const float*)d_in[7];
  const float* Wv  = (const float*)d_in[8];
  const float* bv  = (const float*)d_in[9];
  const float* Wc1 = (const float*)d_in[10];
  const float* bc1 = (const float*)d_in[11];
  const float* Wc2 = (const float*)d_in[12];
  const float* bc2 = (const float*)d_in[13];
  float* out = (float*)d_out;
  u16* ws = (u16*)d_ws;

  u16* Kbuf = ws + 606208;
  u16* Vbuf = ws + 34160640;
  u16* Qbuf = ws + 67715072;
  u16* CI   = ws + 101269504;

  prep_kernel<<<2368, 256, 0, stream>>>(We, Ws, Wk, Wq, Wv, Wc1, ws);
  k1_kernel<<<dim3(256, 8), 512, 0, stream>>>(states, actions, be, bs, bv, ws,
                                              Kbuf, Vbuf, Qbuf, CI);
  k2_kernel<<<2048, 512, 0, stream>>>(Kbuf, Vbuf, Qbuf, CI);
  k3_kernel<<<dim3(256, 8), 512, 0, stream>>>(CI, ws + 344064, bc1, Wc2, bc2, actions, out);
}